// Round 1
// baseline (19323.659 us; speedup 1.0000x reference)
//
#include <hip/hip_runtime.h>
#include <math.h>

static constexpr int BATCH = 64;
static constexpr int NR  = 512;    // rows per matrix (n)
static constexpr int ND  = 384;    // feature dim (N)
static constexpr int RK  = 24;     // rank
static constexpr int NSI = 5;      // Newton-Schulz iters (whitening)
static constexpr int POLAR_ITERS = 36;
static constexpr long SZC = (long)BATCH * ND * ND;      // 9,437,184 floats
static constexpr int SSTR = BATCH * RK;                 // 1536 (inverse-iter solve stride)

#define MODE_PLAIN 0
#define MODE_COV   1
#define MODE_NST   2
#define MODE_SCALE 3
#define MODE_ACC   4

// ---------------- generic batched tiled SGEMM ----------------
// TA=0: C = A(MxK,row-major) * B(KxN,row-major)
// TA=1: C = A^T * B, A stored KxM row-major (lda = M-ish row length)
template<int TA>
__global__ __launch_bounds__(256)
void gemm_kernel(const float* __restrict__ Ag, const float* __restrict__ Bg,
                 float* __restrict__ Cg, int M, int N, int K,
                 long sA, long sB, long sC, int lda, int ldb, int ldc,
                 int mode, const float* __restrict__ scale)
{
    const int batch = blockIdx.y;
    const int tilesN = N >> 6;
    const int tx = blockIdx.x % tilesN;
    const int ty = blockIdx.x / tilesN;
    const int n0 = tx * 64, m0 = ty * 64;
    const float* A = Ag + (long)batch * sA;
    const float* Bm = Bg + (long)batch * sB;
    float* C = Cg + (long)batch * sC;

    __shared__ float As[16][68];
    __shared__ float Bs[16][68];

    const int tid = threadIdx.x;
    const int tr = tid >> 4, tc = tid & 15;

    float acc[4][4];
#pragma unroll
    for (int i = 0; i < 4; i++)
#pragma unroll
        for (int j = 0; j < 4; j++) acc[i][j] = 0.f;

    for (int k0 = 0; k0 < K; k0 += 16) {
        if (TA) {
#pragma unroll
            for (int l = tid; l < 1024; l += 256) {
                int m = l & 63, kk = l >> 6;
                As[kk][m] = A[(long)(k0 + kk) * lda + m0 + m];
            }
        } else {
#pragma unroll
            for (int l = tid; l < 1024; l += 256) {
                int kk = l & 15, m = l >> 4;
                As[kk][m] = A[(long)(m0 + m) * lda + k0 + kk];
            }
        }
#pragma unroll
        for (int l = tid; l < 1024; l += 256) {
            int n = l & 63, kk = l >> 6;
            Bs[kk][n] = Bm[(long)(k0 + kk) * ldb + n0 + n];
        }
        __syncthreads();
#pragma unroll
        for (int kk = 0; kk < 16; kk++) {
            float a0 = As[kk][tr * 4 + 0], a1 = As[kk][tr * 4 + 1];
            float a2 = As[kk][tr * 4 + 2], a3 = As[kk][tr * 4 + 3];
            float b0 = Bs[kk][tc * 4 + 0], b1 = Bs[kk][tc * 4 + 1];
            float b2 = Bs[kk][tc * 4 + 2], b3 = Bs[kk][tc * 4 + 3];
            acc[0][0] += a0 * b0; acc[0][1] += a0 * b1; acc[0][2] += a0 * b2; acc[0][3] += a0 * b3;
            acc[1][0] += a1 * b0; acc[1][1] += a1 * b1; acc[1][2] += a1 * b2; acc[1][3] += a1 * b3;
            acc[2][0] += a2 * b0; acc[2][1] += a2 * b1; acc[2][2] += a2 * b2; acc[2][3] += a2 * b3;
            acc[3][0] += a3 * b0; acc[3][1] += a3 * b1; acc[3][2] += a3 * b2; acc[3][3] += a3 * b3;
        }
        __syncthreads();
    }

    float scl = 1.f;
    if (mode == MODE_SCALE) scl = 1.0f / sqrtf(scale[batch]);

#pragma unroll
    for (int i = 0; i < 4; i++) {
        int gm = m0 + tr * 4 + i;
        float* crow = C + (long)gm * ldc + n0 + tc * 4;
#pragma unroll
        for (int j = 0; j < 4; j++) {
            int gn = n0 + tc * 4 + j;
            float v = acc[i][j];
            if (mode == MODE_COV)      v = v * (1.0f / 512.0f) + ((gm == gn) ? 1e-5f : 0.f);
            else if (mode == MODE_NST) v = ((gm == gn) ? 1.5f : 0.f) - 0.5f * v;
            else if (mode == MODE_SCALE) v *= scl;
            else if (mode == MODE_ACC) v += crow[j];
            crow[j] = v;
        }
    }
}

// ---------------- Frobenius norm per batch ----------------
__global__ __launch_bounds__(256)
void frob_kernel(const float* __restrict__ Cm, float* __restrict__ nrm)
{
    int b = blockIdx.x;
    const float* p = Cm + (long)b * ND * ND;
    float s = 0.f;
    for (int i = threadIdx.x; i < ND * ND; i += 256) { float v = p[i]; s += v * v; }
    __shared__ float red[256];
    red[threadIdx.x] = s; __syncthreads();
    for (int off = 128; off > 0; off >>= 1) {
        if (threadIdx.x < off) red[threadIdx.x] += red[threadIdx.x + off];
        __syncthreads();
    }
    if (threadIdx.x == 0) nrm[b] = sqrtf(red[0]);
}

// ---------------- Y0 = C/normC (in place), Z0 = I ----------------
__global__ __launch_bounds__(256)
void init_kernel(float* __restrict__ Y, float* __restrict__ Z, const float* __restrict__ nrm)
{
    const int total = BATCH * ND * ND;
    for (int idx = blockIdx.x * 256 + threadIdx.x; idx < total; idx += gridDim.x * 256) {
        int b = idx / (ND * ND);
        int rem = idx - b * (ND * ND);
        int r = rem / ND, c = rem - r * ND;
        Y[idx] = Y[idx] / nrm[b];
        Z[idx] = (r == c) ? 1.f : 0.f;
    }
}

// ---------------- Householder tridiagonalization (one WG per batch) ----------------
__global__ __launch_bounds__(512)
void tridiag_kernel(float* __restrict__ Gall, float* __restrict__ dA,
                    float* __restrict__ eA, float* __restrict__ tauA)
{
    int b = blockIdx.x;
    float* A = Gall + (long)b * ND * ND;
    float* d = dA + b * ND; float* e = eA + b * ND; float* tau = tauA + b * ND;
    const int t = threadIdx.x;
    __shared__ float u[ND], w[ND];
    __shared__ float red[512];
    __shared__ float s_tau;

    for (int k = 0; k <= ND - 3; k++) {
        int m = ND - 1 - k;
        float partial = 0.f;
        if (t < m) { float v = A[(long)(k + 1 + t) * ND + k]; u[t] = v; partial = v * v; }
        red[t] = partial; __syncthreads();
        for (int off = 256; off > 0; off >>= 1) {
            if (t < off) red[t] += red[t + off];
            __syncthreads();
        }
        if (t == 0) {
            float sigma = red[0];
            float v0 = u[0];
            float normx = sqrtf(sigma);
            float alpha = (v0 >= 0.f) ? -normx : normx;
            float denom = sigma - alpha * v0;
            float tk = (denom > 1e-30f) ? 1.f / denom : 0.f;   // tau = 2/||u'||^2
            s_tau = tk;
            e[k] = alpha; tau[k] = tk; d[k] = A[(long)k * ND + k];
            u[0] = v0 - alpha;
        }
        __syncthreads();
        float tk = s_tau;
        // p = tau * A_trail * u  (row per thread)
        float pt = 0.f;
        if (t < m) {
            const float* row = A + (long)(k + 1 + t) * ND + (k + 1);
            float a0 = 0, a1 = 0, a2 = 0, a3 = 0;
            int j = 0;
            for (; j + 4 <= m; j += 4) {
                a0 += row[j] * u[j]; a1 += row[j + 1] * u[j + 1];
                a2 += row[j + 2] * u[j + 2]; a3 += row[j + 3] * u[j + 3];
            }
            for (; j < m; j++) a0 += row[j] * u[j];
            pt = tk * (a0 + a1 + a2 + a3);
            w[t] = pt;
        }
        red[t] = (t < m) ? u[t] * pt : 0.f; __syncthreads();
        for (int off = 256; off > 0; off >>= 1) {
            if (t < off) red[t] += red[t + off];
            __syncthreads();
        }
        float sc = 0.5f * tk * red[0];
        if (t < m) w[t] = pt - sc * u[t];
        __syncthreads();
        // rank-2 update (full symmetric trailing block) + store u into column k
        for (int i = t; i < m; i += 512) {
            float ui = u[i], wi = w[i];
            float* row = A + (long)(k + 1 + i) * ND + (k + 1);
            for (int j = 0; j < m; j++) row[j] -= ui * w[j] + wi * u[j];
        }
        if (t < m) A[(long)(k + 1 + t) * ND + k] = u[t];
        __syncthreads();
    }
    if (t == 0) {
        d[ND - 2] = A[(long)(ND - 2) * ND + ND - 2];
        d[ND - 1] = A[(long)(ND - 1) * ND + ND - 1];
        e[ND - 2] = A[(long)(ND - 1) * ND + ND - 2];
        e[ND - 1] = 0.f; tau[ND - 2] = 0.f; tau[ND - 1] = 0.f;
    }
}

// ---------------- Sturm bisection: top-24 eigenvalues ----------------
__global__ __launch_bounds__(64)
void eigvals_kernel(const float* __restrict__ dA, const float* __restrict__ eA,
                    float* __restrict__ lamA)
{
    int b = blockIdx.x, t = threadIdx.x;   // 64 threads
    __shared__ float d[ND], e2[ND], ea[ND], red[64];
    for (int i = t; i < ND; i += 64) {
        d[i] = dA[b * ND + i];
        float ev = eA[b * ND + i];
        ea[i] = fabsf(ev); e2[i] = ev * ev;
    }
    __syncthreads();
    float lo = 1e30f, hi = -1e30f;
    for (int i = t; i < ND; i += 64) {
        float r = ea[i] + ((i > 0) ? ea[i - 1] : 0.f);
        lo = fminf(lo, d[i] - r); hi = fmaxf(hi, d[i] + r);
    }
    red[t] = lo; __syncthreads();
    for (int off = 32; off > 0; off >>= 1) {
        if (t < off) red[t] = fminf(red[t], red[t + off]);
        __syncthreads();
    }
    lo = red[0]; __syncthreads();
    red[t] = hi; __syncthreads();
    for (int off = 32; off > 0; off >>= 1) {
        if (t < off) red[t] = fmaxf(red[t], red[t + off]);
        __syncthreads();
    }
    hi = red[0];
    if (t < RK) {
        int idx = ND - 1 - t;          // ascending index (t=0 -> largest)
        float a = lo, c = hi;
        for (int it = 0; it < 42; it++) {
            float mid = 0.5f * (a + c);
            int cnt = 0;
            float q = d[0] - mid;
            if (q < 0.f) cnt++;
            for (int i = 1; i < ND; i++) {
                float den = q;
                if (fabsf(den) < 1e-25f) den = (den < 0.f) ? -1e-25f : 1e-25f;
                q = d[i] - mid - e2[i - 1] / den;
                if (q < 0.f) cnt++;
            }
            if (cnt > idx) c = mid; else a = mid;
        }
        lamA[b * RK + t] = 0.5f * (a + c);
    }
}

// ---------------- tridiagonal inverse iteration (pivoted LU) ----------------
__global__ __launch_bounds__(64)
void invit_kernel(const float* __restrict__ dA, const float* __restrict__ eA,
                  const float* __restrict__ lamA, float* __restrict__ scr)
{
    int b = blockIdx.x, t = threadIdx.x;
    __shared__ float d[ND], e[ND];
    for (int i = t; i < ND; i += 64) { d[i] = dA[b * ND + i]; e[i] = eA[b * ND + i]; }
    __syncthreads();
    if (t >= RK) return;
    const int s = b * RK + t;
    float* ua = scr;
    float* ub = scr + (long)ND * SSTR;
    float* uc = scr + 2L * ND * SSTR;
    float* ul = scr + 3L * ND * SSTR;
    float* up = scr + 4L * ND * SSTR;
    float* y  = scr + 5L * ND * SSTR;
    float lam = lamA[s];
    // factor T - lam*I with partial pivoting (slagtf-style)
    float ai = d[0] - lam;
    float bc = e[0];
    for (int i = 0; i < ND - 1; i++) {
        float sub = e[i];
        float dn = d[i + 1] - lam;
        float en = (i + 1 < ND - 1) ? e[i + 1] : 0.f;
        long o = (long)i * SSTR + s;
        if (fabsf(ai) >= fabsf(sub)) {
            float aa = (ai == 0.f) ? 1e-20f : ai;
            float mlt = sub / aa;
            ua[o] = aa; ub[o] = bc; uc[o] = 0.f; ul[o] = mlt; up[o] = 0.f;
            ai = dn - mlt * bc;
            bc = en;
        } else {
            float mlt = ai / sub;
            ua[o] = sub; ub[o] = dn; uc[o] = en; ul[o] = mlt; up[o] = 1.f;
            ai = bc - mlt * dn;
            bc = -mlt * en;
        }
    }
    { long o = (long)(ND - 1) * SSTR + s; ua[o] = (ai == 0.f) ? 1e-20f : ai; ub[o] = 0.f; uc[o] = 0.f; }

    for (int pass = 0; pass < 2; pass++) {
        if (pass == 0) {
            for (int i = 0; i < ND; i++) {
                unsigned h = ((unsigned)i * 1103515245u) ^ ((unsigned)s * 747796405u);
                h *= 2654435769u; h ^= h >> 16;
                y[(long)i * SSTR + s] = ((float)(h & 0xFFFFu) * (1.f / 65536.f)) - 0.5f;
            }
        }
        // forward substitution with pivot replay
        for (int i = 0; i < ND - 1; i++) {
            long o = (long)i * SSTR + s, o1 = o + SSTR;
            float yi = y[o], y1 = y[o1];
            if (up[o] == 0.f) { y[o1] = y1 - ul[o] * yi; }
            else { y[o] = y1; y[o1] = yi - ul[o] * y1; }
        }
        // back substitution (two superdiagonals)
        {
            long oN = (long)(ND - 1) * SSTR + s;
            float xN = y[oN] / ua[oN]; y[oN] = xN;
            long o = oN - SSTR;
            float x1 = xN, x2 = 0.f;
            float xm = (y[o] - ub[o] * x1) / ua[o]; y[o] = xm; x2 = x1; x1 = xm;
            for (int i = ND - 3; i >= 0; i--) {
                o -= SSTR;
                float xi = (y[o] - ub[o] * x1 - uc[o] * x2) / ua[o];
                y[o] = xi; x2 = x1; x1 = xi;
            }
        }
        float nn = 0.f;
        for (int i = 0; i < ND; i++) { float v = y[(long)i * SSTR + s]; nn += v * v; }
        float inv = (nn > 0.f) ? 1.f / sqrtf(nn) : 0.f;
        for (int i = 0; i < ND; i++) y[(long)i * SSTR + s] *= inv;
    }
}

// ---------------- MGS + Householder back-transform (one WG per batch) ----------------
__device__ __forceinline__ float blockSum384(float v, float* red6, int t)
{
#pragma unroll
    for (int off = 32; off > 0; off >>= 1) v += __shfl_down(v, off);
    __syncthreads();
    if ((t & 63) == 0) red6[t >> 6] = v;
    __syncthreads();
    return red6[0] + red6[1] + red6[2] + red6[3] + red6[4] + red6[5];
}

__global__ __launch_bounds__(384)
void orthbt_kernel(const float* __restrict__ xx, const float* __restrict__ Gall,
                   const float* __restrict__ tauA, float* __restrict__ Qout)
{
    int b = blockIdx.x, t = threadIdx.x;   // 384 threads
    __shared__ float Y[ND][RK + 1];
    __shared__ float u[ND];
    __shared__ float red[ND];
    __shared__ float red6[8];
    __shared__ float sarr[RK];

    for (int j = 0; j < RK; j++) Y[t][j] = xx[(long)t * SSTR + b * RK + j];
    __syncthreads();

    // modified Gram-Schmidt (row-local updates)
    for (int j = 0; j < RK; j++) {
        float nv = blockSum384(Y[t][j] * Y[t][j], red6, t);
        float inv = (nv > 1e-30f) ? 1.f / sqrtf(nv) : 0.f;
        Y[t][j] *= inv;
        for (int l = j + 1; l < RK; l++) {
            float dt = blockSum384(Y[t][j] * Y[t][l], red6, t);
            Y[t][l] -= dt * Y[t][j];
        }
    }
    __syncthreads();

    const float* A = Gall + (long)b * ND * ND;
    const float* tau = tauA + b * ND;
    const int col = t % RK;       // 384 = 16*24
    const int sl = t / RK;
    for (int k = ND - 3; k >= 0; k--) {
        int m = ND - 1 - k;
        for (int i = t; i < m; i += 384) u[i] = A[(long)(k + 1 + i) * ND + k];
        float tk = tau[k];
        __syncthreads();
        float p = 0.f;
        for (int i = sl; i < m; i += 16) p += u[i] * Y[k + 1 + i][col];
        red[col * 16 + sl] = p; __syncthreads();
        if (sl == 0) {
            float ssum = 0.f;
            for (int q = 0; q < 16; q++) ssum += red[col * 16 + q];
            sarr[col] = tk * ssum;
        }
        __syncthreads();
        float sv = sarr[col];
        for (int i = sl; i < m; i += 16) Y[k + 1 + i][col] -= u[i] * sv;
        __syncthreads();
    }
    for (int l = t; l < ND * RK; l += 384) {
        int i = l / RK, j = l - i * RK;
        Qout[(long)b * ND * RK + l] = Y[i][j];
    }
}

// ---------------- Sp = X_w @ Q ----------------
__global__ __launch_bounds__(256)
void proj_kernel(const float* __restrict__ Xw, const float* __restrict__ Qall,
                 float* __restrict__ P)
{
    int b = blockIdx.y;
    int r0 = blockIdx.x * 256;
    __shared__ float Qs[ND][RK + 1];
    const float* Q = Qall + (long)b * ND * RK;
    for (int l = threadIdx.x; l < ND * RK; l += 256) {
        int i = l / RK, j = l - i * RK;
        Qs[i][j] = Q[l];
    }
    __syncthreads();
    int r = r0 + threadIdx.x;
    const float* X = Xw + (long)b * NR * ND + (long)r * ND;
    float acc[RK];
#pragma unroll
    for (int j = 0; j < RK; j++) acc[j] = 0.f;
    for (int k = 0; k < ND; k++) {
        float xv = X[k];
#pragma unroll
        for (int j = 0; j < RK; j++) acc[j] += xv * Qs[k][j];
    }
    float* Pr = P + (long)b * NR * RK + (long)r * RK;
#pragma unroll
    for (int j = 0; j < RK; j++) Pr[j] = acc[j];
}

// ---------------- M = Sp^T Tp ; R = polar(M) via Newton-Schulz ; write R - I ----------------
__global__ __launch_bounds__(256)
void polar_kernel(const float* __restrict__ Sp, const float* __restrict__ Tp,
                  float* __restrict__ RmI)
{
    int b = blockIdx.x, t = threadIdx.x;
    __shared__ float Sb[128][RK + 1], Tb[128][RK + 1];
    __shared__ float Xm[RK][RK + 1], Bm[RK][RK + 1], Mm[RK][RK + 1];
    __shared__ float red[256];

    float accM[3] = {0.f, 0.f, 0.f};
    for (int c = 0; c < 4; c++) {
        for (int l = t; l < 128 * RK; l += 256) {
            int row = l / RK, colj = l - row * RK;
            Sb[row][colj] = Sp[(long)b * NR * RK + (long)(c * 128 + row) * RK + colj];
            Tb[row][colj] = Tp[(long)b * NR * RK + (long)(c * 128 + row) * RK + colj];
        }
        __syncthreads();
        for (int q = 0; q < 3; q++) {
            int e = t + q * 256;
            if (e < RK * RK) {
                int r = e / RK, s2 = e - r * RK;
                float a = 0.f;
                for (int n = 0; n < 128; n++) a += Sb[n][r] * Tb[n][s2];
                accM[q] += a;
            }
        }
        __syncthreads();
    }
    float ss = 0.f;
    for (int q = 0; q < 3; q++) {
        int e = t + q * 256;
        if (e < RK * RK) {
            int r = e / RK, s2 = e - r * RK;
            Mm[r][s2] = accM[q];
            ss += accM[q] * accM[q];
        }
    }
    red[t] = ss; __syncthreads();
    for (int off = 128; off > 0; off >>= 1) {
        if (t < off) red[t] += red[t + off];
        __syncthreads();
    }
    float fro = sqrtf(red[0]);
    float inv = (fro > 1e-30f) ? 1.f / fro : 0.f;
    for (int q = 0; q < 3; q++) {
        int e = t + q * 256;
        if (e < RK * RK) { int r = e / RK, s2 = e - r * RK; Xm[r][s2] = Mm[r][s2] * inv; }
    }
    __syncthreads();
    for (int it = 0; it < POLAR_ITERS; it++) {
        // B = X^T X
        for (int q = 0; q < 3; q++) {
            int e = t + q * 256;
            if (e < RK * RK) {
                int r = e / RK, s2 = e - r * RK;
                float a = 0.f;
                for (int k = 0; k < RK; k++) a += Xm[k][r] * Xm[k][s2];
                Bm[r][s2] = a;
            }
        }
        __syncthreads();
        // Xn = 1.5 X - 0.5 X B
        for (int q = 0; q < 3; q++) {
            int e = t + q * 256;
            if (e < RK * RK) {
                int r = e / RK, s2 = e - r * RK;
                float a = 0.f;
                for (int k = 0; k < RK; k++) a += Xm[r][k] * Bm[k][s2];
                Mm[r][s2] = 1.5f * Xm[r][s2] - 0.5f * a;
            }
        }
        __syncthreads();
        for (int q = 0; q < 3; q++) {
            int e = t + q * 256;
            if (e < RK * RK) { int r = e / RK, s2 = e - r * RK; Xm[r][s2] = Mm[r][s2]; }
        }
        __syncthreads();
    }
    for (int q = 0; q < 3; q++) {
        int e = t + q * 256;
        if (e < RK * RK) {
            int r = e / RK, s2 = e - r * RK;
            RmI[(long)b * RK * RK + e] = Xm[r][s2] - ((r == s2) ? 1.f : 0.f);
        }
    }
}

// ---------------- aligned = S_w + Sp (R-I) Q^T  (writes d_out) ----------------
__global__ __launch_bounds__(256)
void align_kernel(const float* __restrict__ Sw, const float* __restrict__ Sp,
                  const float* __restrict__ RmI, const float* __restrict__ Qall,
                  float* __restrict__ out)
{
    int b = blockIdx.y;
    int r0 = blockIdx.x * 64;
    int t = threadIdx.x;
    __shared__ float Qs[ND][RK + 1];
    __shared__ float Rm[RK][RK + 1];
    __shared__ float Ss[64][RK + 1];
    __shared__ float W[64][RK + 1];

    for (int l = t; l < ND * RK; l += 256) {
        int i = l / RK, j = l - i * RK;
        Qs[i][j] = Qall[(long)b * ND * RK + l];
    }
    for (int l = t; l < RK * RK; l += 256) {
        int i = l / RK, j = l - i * RK;
        Rm[i][j] = RmI[(long)b * RK * RK + l];
    }
    for (int l = t; l < 64 * RK; l += 256) {
        int i = l / RK, j = l - i * RK;
        Ss[i][j] = Sp[(long)b * NR * RK + (long)(r0 + i) * RK + j];
    }
    __syncthreads();
    for (int l = t; l < 64 * RK; l += 256) {
        int r = l / RK, j = l - r * RK;
        float a = 0.f;
        for (int k = 0; k < RK; k++) a += Ss[r][k] * Rm[k][j];
        W[r][j] = a;
    }
    __syncthreads();
    for (int r = 0; r < 64; r++) {
        for (int c = t; c < ND; c += 256) {
            float a = Sw[(long)b * NR * ND + (long)(r0 + r) * ND + c];
            float s2 = 0.f;
#pragma unroll
            for (int j = 0; j < RK; j++) s2 += W[r][j] * Qs[c][j];
            out[(long)b * NR * ND + (long)(r0 + r) * ND + c] = a + s2;
        }
    }
}

// ---------------- mean cosine ----------------
__global__ __launch_bounds__(256)
void cos_kernel(const float* __restrict__ out, const float* __restrict__ tgt,
                float* __restrict__ acc)
{
    int row = blockIdx.x * 4 + (threadIdx.x >> 6);
    int lane = threadIdx.x & 63;
    const float* a = out + (long)row * ND;
    const float* tg = tgt + (long)row * ND;
    float sd = 0.f, sa = 0.f, st = 0.f;
    for (int i = lane; i < ND; i += 64) {
        float av = a[i], tv = tg[i];
        sd += av * tv; sa += av * av; st += tv * tv;
    }
#pragma unroll
    for (int off = 32; off > 0; off >>= 1) {
        sd += __shfl_down(sd, off); sa += __shfl_down(sa, off); st += __shfl_down(st, off);
    }
    __shared__ float part[4];
    if (lane == 0) part[threadIdx.x >> 6] = sd / (sqrtf(sa) * sqrtf(st) + 1e-8f);
    __syncthreads();
    if (threadIdx.x == 0) atomicAdd(acc, part[0] + part[1] + part[2] + part[3]);
}

__global__ void finalize_kernel(const float* __restrict__ acc, float* __restrict__ out)
{
    out[0] = acc[0] / 32768.0f;
}

// ---------------- host ----------------
static inline void launch_gemm(int TA, const float* A, const float* Bm, float* C,
                               int M, int N, int K, long sA, long sB, long sC,
                               int lda, int ldb, int ldc, int mode,
                               const float* scale, hipStream_t stream)
{
    dim3 grid((M / 64) * (N / 64), BATCH);
    if (TA)
        gemm_kernel<1><<<grid, dim3(256), 0, stream>>>(A, Bm, C, M, N, K, sA, sB, sC, lda, ldb, ldc, mode, scale);
    else
        gemm_kernel<0><<<grid, dim3(256), 0, stream>>>(A, Bm, C, M, N, K, sA, sB, sC, lda, ldb, ldc, mode, scale);
}

extern "C" void kernel_launch(void* const* d_in, const int* in_sizes, int n_in,
                              void* d_out, int out_size, void* d_ws, size_t ws_size,
                              hipStream_t stream)
{
    const float* src = (const float*)d_in[0];
    const float* tgt = (const float*)d_in[1];
    float* out = (float*)d_out;
    float* ws = (float*)d_ws;

    // workspace layout (floats); requires ~189 MB of ws
    float* A0 = ws;
    float* A1 = ws + 1 * SZC;
    float* A2 = ws + 2 * SZC;
    float* A3 = ws + 3 * SZC;
    float* A4 = ws + 4 * SZC;
    float* S5 = ws + 5 * SZC;
    float* nrm_s = S5;
    float* nrm_t = S5 + 64;
    float* dd = S5 + 128;
    float* ee = dd + BATCH * ND;
    float* tt = ee + BATCH * ND;
    float* lam = tt + BATCH * ND;
    float* accp = lam + BATCH * RK;

    float* Tm = out;                 // transient NS "T" buffer lives in d_out
    float* SW = A0;                  // 512x384 per batch (spans A0..A1)
    float* TW = A0 + (long)BATCH * NR * ND;   // spans into A2 region
    float* G  = A3;
    // C-region in A4:
    float* scr = A4;                                   // 6 * 384 * 1536
    float* Qp  = A4 + 6L * ND * SSTR;
    float* Spp = Qp + (long)BATCH * ND * RK;
    float* Tpp = Spp + (long)BATCH * NR * RK;
    float* Rp  = Tpp + (long)BATCH * NR * RK;
    float* yarr = scr + 5L * ND * SSTR;

    const long sXin = (long)NR * ND;     // 196608
    const long sSq  = (long)ND * ND;     // 147456

    // ---- phase S: covariance + Newton-Schulz inverse sqrt ----
    launch_gemm(1, src, src, A0, ND, ND, NR, sXin, sXin, sSq, ND, ND, ND, MODE_COV, nullptr, stream);
    frob_kernel<<<BATCH, 256, 0, stream>>>(A0, nrm_s);
    init_kernel<<<dim3(4096), 256, 0, stream>>>(A0, A2, nrm_s);
    {
        float* Y = A0; float* Yo = A1; float* Z = A2; float* Zo = A3;
        for (int it = 0; it < NSI; it++) {
            launch_gemm(0, Z, Y, Tm, ND, ND, ND, sSq, sSq, sSq, ND, ND, ND, MODE_NST, nullptr, stream);
            launch_gemm(0, Y, Tm, Yo, ND, ND, ND, sSq, sSq, sSq, ND, ND, ND, MODE_PLAIN, nullptr, stream);
            launch_gemm(0, Tm, Z, Zo, ND, ND, ND, sSq, sSq, sSq, ND, ND, ND, MODE_PLAIN, nullptr, stream);
            float* tmp = Y; Y = Yo; Yo = tmp;
            tmp = Z; Z = Zo; Zo = tmp;
        }
        // Z_s ends in A3
    }
    // ---- phase T ----
    launch_gemm(1, tgt, tgt, A0, ND, ND, NR, sXin, sXin, sSq, ND, ND, ND, MODE_COV, nullptr, stream);
    frob_kernel<<<BATCH, 256, 0, stream>>>(A0, nrm_t);
    init_kernel<<<dim3(4096), 256, 0, stream>>>(A0, A2, nrm_t);
    {
        float* Y = A0; float* Yo = A1; float* Z = A2; float* Zo = A4;
        for (int it = 0; it < NSI; it++) {
            launch_gemm(0, Z, Y, Tm, ND, ND, ND, sSq, sSq, sSq, ND, ND, ND, MODE_NST, nullptr, stream);
            launch_gemm(0, Y, Tm, Yo, ND, ND, ND, sSq, sSq, sSq, ND, ND, ND, MODE_PLAIN, nullptr, stream);
            launch_gemm(0, Tm, Z, Zo, ND, ND, ND, sSq, sSq, sSq, ND, ND, ND, MODE_PLAIN, nullptr, stream);
            float* tmp = Y; Y = Yo; Yo = tmp;
            tmp = Z; Z = Zo; Zo = tmp;
        }
        // Z_t ends in A4
    }
    // ---- whiten: S_w = S Z_s / sqrt(nrm), T_w = T Z_t / sqrt(nrm) ----
    launch_gemm(0, src, A3, SW, NR, ND, ND, sXin, sSq, sXin, ND, ND, ND, MODE_SCALE, nrm_s, stream);
    launch_gemm(0, tgt, A4, TW, NR, ND, ND, sXin, sSq, sXin, ND, ND, ND, MODE_SCALE, nrm_t, stream);
    // ---- G = S_w^T S_w + T_w^T T_w ----
    launch_gemm(1, SW, SW, G, ND, ND, NR, sXin, sXin, sSq, ND, ND, ND, MODE_PLAIN, nullptr, stream);
    launch_gemm(1, TW, TW, G, ND, ND, NR, sXin, sXin, sSq, ND, ND, ND, MODE_ACC, nullptr, stream);
    // ---- eigensolver: tridiag + bisection + inverse iteration + back-transform ----
    tridiag_kernel<<<BATCH, 512, 0, stream>>>(G, dd, ee, tt);
    eigvals_kernel<<<BATCH, 64, 0, stream>>>(dd, ee, lam);
    invit_kernel<<<BATCH, 64, 0, stream>>>(dd, ee, lam, scr);
    orthbt_kernel<<<BATCH, 384, 0, stream>>>(yarr, G, tt, Qp);
    // ---- projections, Procrustes, output ----
    proj_kernel<<<dim3(2, BATCH), 256, 0, stream>>>(SW, Qp, Spp);
    proj_kernel<<<dim3(2, BATCH), 256, 0, stream>>>(TW, Qp, Tpp);
    polar_kernel<<<BATCH, 256, 0, stream>>>(Spp, Tpp, Rp);
    align_kernel<<<dim3(8, BATCH), 256, 0, stream>>>(SW, Spp, Rp, Qp, out);
    hipMemsetAsync((void*)accp, 0, 4, stream);
    cos_kernel<<<dim3(8192), 256, 0, stream>>>(out, tgt, accp);
    finalize_kernel<<<1, 1, 0, stream>>>(accp, out + (long)BATCH * NR * ND);
    (void)in_sizes; (void)n_in; (void)out_size; (void)ws_size;
}

// Round 2
// 14994.234 us; speedup vs baseline: 1.2887x; 1.2887x over previous
//
#include <hip/hip_runtime.h>
#include <math.h>

static constexpr int BATCH = 64;
static constexpr int NR  = 512;    // rows per matrix (n)
static constexpr int ND  = 384;    // feature dim (N)
static constexpr int RK  = 24;     // rank
static constexpr int NSI = 5;      // Newton-Schulz iters (whitening)
static constexpr int POLAR_ITERS = 36;
static constexpr long SZC = (long)BATCH * ND * ND;      // 9,437,184 floats
static constexpr int SSTR = BATCH * RK;                 // 1536 (inverse-iter solve stride)

#define MODE_PLAIN 0
#define MODE_COV   1
#define MODE_NST   2
#define MODE_SCALE 3
#define MODE_ACC   4

// ---------------- generic batched tiled SGEMM ----------------
// TA=0: C = A(MxK,row-major) * B(KxN,row-major)
// TA=1: C = A^T * B, A stored KxM row-major (lda = M-ish row length)
template<int TA>
__global__ __launch_bounds__(256)
void gemm_kernel(const float* __restrict__ Ag, const float* __restrict__ Bg,
                 float* __restrict__ Cg, int M, int N, int K,
                 long sA, long sB, long sC, int lda, int ldb, int ldc,
                 int mode, const float* __restrict__ scale)
{
    const int batch = blockIdx.y;
    const int tilesN = N >> 6;
    const int tx = blockIdx.x % tilesN;
    const int ty = blockIdx.x / tilesN;
    const int n0 = tx * 64, m0 = ty * 64;
    const float* A = Ag + (long)batch * sA;
    const float* Bm = Bg + (long)batch * sB;
    float* C = Cg + (long)batch * sC;

    __shared__ float As[16][68];
    __shared__ float Bs[16][68];

    const int tid = threadIdx.x;
    const int tr = tid >> 4, tc = tid & 15;

    float acc[4][4];
#pragma unroll
    for (int i = 0; i < 4; i++)
#pragma unroll
        for (int j = 0; j < 4; j++) acc[i][j] = 0.f;

    for (int k0 = 0; k0 < K; k0 += 16) {
        if (TA) {
#pragma unroll
            for (int l = tid; l < 1024; l += 256) {
                int m = l & 63, kk = l >> 6;
                As[kk][m] = A[(long)(k0 + kk) * lda + m0 + m];
            }
        } else {
#pragma unroll
            for (int l = tid; l < 1024; l += 256) {
                int kk = l & 15, m = l >> 4;
                As[kk][m] = A[(long)(m0 + m) * lda + k0 + kk];
            }
        }
#pragma unroll
        for (int l = tid; l < 1024; l += 256) {
            int n = l & 63, kk = l >> 6;
            Bs[kk][n] = Bm[(long)(k0 + kk) * ldb + n0 + n];
        }
        __syncthreads();
#pragma unroll
        for (int kk = 0; kk < 16; kk++) {
            float a0 = As[kk][tr * 4 + 0], a1 = As[kk][tr * 4 + 1];
            float a2 = As[kk][tr * 4 + 2], a3 = As[kk][tr * 4 + 3];
            float b0 = Bs[kk][tc * 4 + 0], b1 = Bs[kk][tc * 4 + 1];
            float b2 = Bs[kk][tc * 4 + 2], b3 = Bs[kk][tc * 4 + 3];
            acc[0][0] += a0 * b0; acc[0][1] += a0 * b1; acc[0][2] += a0 * b2; acc[0][3] += a0 * b3;
            acc[1][0] += a1 * b0; acc[1][1] += a1 * b1; acc[1][2] += a1 * b2; acc[1][3] += a1 * b3;
            acc[2][0] += a2 * b0; acc[2][1] += a2 * b1; acc[2][2] += a2 * b2; acc[2][3] += a2 * b3;
            acc[3][0] += a3 * b0; acc[3][1] += a3 * b1; acc[3][2] += a3 * b2; acc[3][3] += a3 * b3;
        }
        __syncthreads();
    }

    float scl = 1.f;
    if (mode == MODE_SCALE) scl = 1.0f / sqrtf(scale[batch]);

#pragma unroll
    for (int i = 0; i < 4; i++) {
        int gm = m0 + tr * 4 + i;
        float* crow = C + (long)gm * ldc + n0 + tc * 4;
#pragma unroll
        for (int j = 0; j < 4; j++) {
            int gn = n0 + tc * 4 + j;
            float v = acc[i][j];
            if (mode == MODE_COV)      v = v * (1.0f / 512.0f) + ((gm == gn) ? 1e-5f : 0.f);
            else if (mode == MODE_NST) v = ((gm == gn) ? 1.5f : 0.f) - 0.5f * v;
            else if (mode == MODE_SCALE) v *= scl;
            else if (mode == MODE_ACC) v += crow[j];
            crow[j] = v;
        }
    }
}

// ---------------- Frobenius norm per batch ----------------
__global__ __launch_bounds__(256)
void frob_kernel(const float* __restrict__ Cm, float* __restrict__ nrm)
{
    int b = blockIdx.x;
    const float* p = Cm + (long)b * ND * ND;
    float s = 0.f;
    for (int i = threadIdx.x; i < ND * ND; i += 256) { float v = p[i]; s += v * v; }
    __shared__ float red[256];
    red[threadIdx.x] = s; __syncthreads();
    for (int off = 128; off > 0; off >>= 1) {
        if (threadIdx.x < off) red[threadIdx.x] += red[threadIdx.x + off];
        __syncthreads();
    }
    if (threadIdx.x == 0) nrm[b] = sqrtf(red[0]);
}

// ---------------- Y0 = C/normC (in place), Z0 = I ----------------
__global__ __launch_bounds__(256)
void init_kernel(float* __restrict__ Y, float* __restrict__ Z, const float* __restrict__ nrm)
{
    const int total = BATCH * ND * ND;
    for (int idx = blockIdx.x * 256 + threadIdx.x; idx < total; idx += gridDim.x * 256) {
        int b = idx / (ND * ND);
        int rem = idx - b * (ND * ND);
        int r = rem / ND, c = rem - r * ND;
        Y[idx] = Y[idx] / nrm[b];
        Z[idx] = (r == c) ? 1.f : 0.f;
    }
}

// ---------------- block reduction over 384 threads ----------------
__device__ __forceinline__ float bred384(float v, float* red6, int t)
{
#pragma unroll
    for (int off = 32; off > 0; off >>= 1) v += __shfl_down(v, off);
    if ((t & 63) == 0) red6[t >> 6] = v;
    __syncthreads();
    float r = red6[0] + red6[1] + red6[2] + red6[3] + red6[4] + red6[5];
    __syncthreads();
    return r;
}

// ---------------- Householder tridiagonalization (row-reflector, column-parallel) ----
// Symmetric A: reflector at step k = row k's trailing part (contiguous, coalesced).
// Matvec and rank-2 update sweep rows with lane t owning column t: every global
// access is a full coalesced wave transaction; trailing block stays L2-resident.
// Reflector u_k is stored back into row k (columns k+1..), coalesced.
__global__ __launch_bounds__(384)
void tridiag_kernel(float* __restrict__ Gall, float* __restrict__ dA,
                    float* __restrict__ eA, float* __restrict__ tauA)
{
    int b = blockIdx.x;
    float* A = Gall + (long)b * ND * ND;
    float* d = dA + b * ND; float* e = eA + b * ND; float* tau = tauA + b * ND;
    const int t = threadIdx.x;
    __shared__ float u_s[ND], w_s[ND];
    __shared__ float red6[8];
    __shared__ float s_tau;

    for (int k = 0; k <= ND - 3; k++) {
        const int m = ND - 1 - k;
        float* rowk = A + (long)k * ND + (k + 1);
        float v = 0.f;
        if (t < m) { v = rowk[t]; u_s[t] = v; }
        float sigma = bred384(v * v, red6, t);   // sync inside makes u_s visible
        if (t == 0) {
            float v0 = u_s[0];
            float normx = sqrtf(sigma);
            float alpha = (v0 >= 0.f) ? -normx : normx;
            float denom = sigma - alpha * v0;
            float tk = (denom > 1e-30f) ? 1.f / denom : 0.f;   // tau = 2/||u||^2
            s_tau = tk;
            e[k] = alpha; tau[k] = tk; d[k] = A[(long)k * ND + k];
            u_s[0] = v0 - alpha;
        }
        __syncthreads();
        const float tk = s_tau;

        // p_t = tk * sum_i A[k+1+i][k+1+t] * u_s[i]   (coalesced row sweep)
        float p = 0.f;
        if (t < m) {
            const float* col = A + (long)(k + 1) * ND + (k + 1) + t;
            int i = 0;
            for (; i + 4 <= m; i += 4) {
                p += col[(long)(i    ) * ND] * u_s[i];
                p += col[(long)(i + 1) * ND] * u_s[i + 1];
                p += col[(long)(i + 2) * ND] * u_s[i + 2];
                p += col[(long)(i + 3) * ND] * u_s[i + 3];
            }
            for (; i < m; i++) p += col[(long)i * ND] * u_s[i];
            p *= tk;
        }
        float dotup = bred384((t < m) ? u_s[t] * p : 0.f, red6, t);
        float sc = 0.5f * tk * dotup;
        if (t < m) w_s[t] = p - sc * u_s[t];
        __syncthreads();

        // A_trail -= u w^T + w u^T  (full symmetric block, coalesced row sweep)
        if (t < m) {
            const float ut = u_s[t], wt = w_s[t];
            float* col = A + (long)(k + 1) * ND + (k + 1) + t;
            int i = 0;
            for (; i + 2 <= m; i += 2) {
                float a0 = col[(long)(i    ) * ND] - (u_s[i    ] * wt + w_s[i    ] * ut);
                float a1 = col[(long)(i + 1) * ND] - (u_s[i + 1] * wt + w_s[i + 1] * ut);
                col[(long)(i    ) * ND] = a0;
                col[(long)(i + 1) * ND] = a1;
            }
            for (; i < m; i++) col[(long)i * ND] -= (u_s[i] * wt + w_s[i] * ut);
            rowk[t] = ut;   // store reflector into row k (coalesced)
        }
        __syncthreads();
    }
    if (t == 0) {
        d[ND - 2] = A[(long)(ND - 2) * ND + (ND - 2)];
        d[ND - 1] = A[(long)(ND - 1) * ND + (ND - 1)];
        e[ND - 2] = A[(long)(ND - 2) * ND + (ND - 1)];
        e[ND - 1] = 0.f; tau[ND - 2] = 0.f; tau[ND - 1] = 0.f;
    }
}

// ---------------- Sturm bisection: top-24 eigenvalues ----------------
__global__ __launch_bounds__(64)
void eigvals_kernel(const float* __restrict__ dA, const float* __restrict__ eA,
                    float* __restrict__ lamA)
{
    int b = blockIdx.x, t = threadIdx.x;   // 64 threads
    __shared__ float d[ND], e2[ND], ea[ND], red[64];
    for (int i = t; i < ND; i += 64) {
        d[i] = dA[b * ND + i];
        float ev = eA[b * ND + i];
        ea[i] = fabsf(ev); e2[i] = ev * ev;
    }
    __syncthreads();
    float lo = 1e30f, hi = -1e30f;
    for (int i = t; i < ND; i += 64) {
        float r = ea[i] + ((i > 0) ? ea[i - 1] : 0.f);
        lo = fminf(lo, d[i] - r); hi = fmaxf(hi, d[i] + r);
    }
    red[t] = lo; __syncthreads();
    for (int off = 32; off > 0; off >>= 1) {
        if (t < off) red[t] = fminf(red[t], red[t + off]);
        __syncthreads();
    }
    lo = red[0]; __syncthreads();
    red[t] = hi; __syncthreads();
    for (int off = 32; off > 0; off >>= 1) {
        if (t < off) red[t] = fmaxf(red[t], red[t + off]);
        __syncthreads();
    }
    hi = red[0];
    if (t < RK) {
        int idx = ND - 1 - t;          // ascending index (t=0 -> largest)
        float a = lo, c = hi;
        for (int it = 0; it < 42; it++) {
            float mid = 0.5f * (a + c);
            int cnt = 0;
            float q = d[0] - mid;
            if (q < 0.f) cnt++;
            for (int i = 1; i < ND; i++) {
                float den = q;
                if (fabsf(den) < 1e-25f) den = (den < 0.f) ? -1e-25f : 1e-25f;
                q = d[i] - mid - e2[i - 1] / den;
                if (q < 0.f) cnt++;
            }
            if (cnt > idx) c = mid; else a = mid;
        }
        lamA[b * RK + t] = 0.5f * (a + c);
    }
}

// ---------------- tridiagonal inverse iteration (pivoted LU) ----------------
__global__ __launch_bounds__(64)
void invit_kernel(const float* __restrict__ dA, const float* __restrict__ eA,
                  const float* __restrict__ lamA, float* __restrict__ scr)
{
    int b = blockIdx.x, t = threadIdx.x;
    __shared__ float d[ND], e[ND];
    for (int i = t; i < ND; i += 64) { d[i] = dA[b * ND + i]; e[i] = eA[b * ND + i]; }
    __syncthreads();
    if (t >= RK) return;
    const int s = b * RK + t;
    float* ua = scr;
    float* ub = scr + (long)ND * SSTR;
    float* uc = scr + 2L * ND * SSTR;
    float* ul = scr + 3L * ND * SSTR;
    float* up = scr + 4L * ND * SSTR;
    float* y  = scr + 5L * ND * SSTR;
    float lam = lamA[s];
    // factor T - lam*I with partial pivoting (slagtf-style)
    float ai = d[0] - lam;
    float bc = e[0];
    for (int i = 0; i < ND - 1; i++) {
        float sub = e[i];
        float dn = d[i + 1] - lam;
        float en = (i + 1 < ND - 1) ? e[i + 1] : 0.f;
        long o = (long)i * SSTR + s;
        if (fabsf(ai) >= fabsf(sub)) {
            float aa = (ai == 0.f) ? 1e-20f : ai;
            float mlt = sub / aa;
            ua[o] = aa; ub[o] = bc; uc[o] = 0.f; ul[o] = mlt; up[o] = 0.f;
            ai = dn - mlt * bc;
            bc = en;
        } else {
            float mlt = ai / sub;
            ua[o] = sub; ub[o] = dn; uc[o] = en; ul[o] = mlt; up[o] = 1.f;
            ai = bc - mlt * dn;
            bc = -mlt * en;
        }
    }
    { long o = (long)(ND - 1) * SSTR + s; ua[o] = (ai == 0.f) ? 1e-20f : ai; ub[o] = 0.f; uc[o] = 0.f; }

    for (int pass = 0; pass < 2; pass++) {
        if (pass == 0) {
            for (int i = 0; i < ND; i++) {
                unsigned h = ((unsigned)i * 1103515245u) ^ ((unsigned)s * 747796405u);
                h *= 2654435769u; h ^= h >> 16;
                y[(long)i * SSTR + s] = ((float)(h & 0xFFFFu) * (1.f / 65536.f)) - 0.5f;
            }
        }
        // forward substitution with pivot replay
        for (int i = 0; i < ND - 1; i++) {
            long o = (long)i * SSTR + s, o1 = o + SSTR;
            float yi = y[o], y1 = y[o1];
            if (up[o] == 0.f) { y[o1] = y1 - ul[o] * yi; }
            else { y[o] = y1; y[o1] = yi - ul[o] * y1; }
        }
        // back substitution (two superdiagonals)
        {
            long oN = (long)(ND - 1) * SSTR + s;
            float xN = y[oN] / ua[oN]; y[oN] = xN;
            long o = oN - SSTR;
            float x1 = xN, x2 = 0.f;
            float xm = (y[o] - ub[o] * x1) / ua[o]; y[o] = xm; x2 = x1; x1 = xm;
            for (int i = ND - 3; i >= 0; i--) {
                o -= SSTR;
                float xi = (y[o] - ub[o] * x1 - uc[o] * x2) / ua[o];
                y[o] = xi; x2 = x1; x1 = xi;
            }
        }
        float nn = 0.f;
        for (int i = 0; i < ND; i++) { float v = y[(long)i * SSTR + s]; nn += v * v; }
        float inv = (nn > 0.f) ? 1.f / sqrtf(nn) : 0.f;
        for (int i = 0; i < ND; i++) y[(long)i * SSTR + s] *= inv;
    }
}

// ---------------- MGS + Householder back-transform (one WG per batch) ----------------
__device__ __forceinline__ float blockSum384(float v, float* red6, int t)
{
#pragma unroll
    for (int off = 32; off > 0; off >>= 1) v += __shfl_down(v, off);
    __syncthreads();
    if ((t & 63) == 0) red6[t >> 6] = v;
    __syncthreads();
    return red6[0] + red6[1] + red6[2] + red6[3] + red6[4] + red6[5];
}

__global__ __launch_bounds__(384)
void orthbt_kernel(const float* __restrict__ xx, const float* __restrict__ Gall,
                   const float* __restrict__ tauA, float* __restrict__ Qout)
{
    int b = blockIdx.x, t = threadIdx.x;   // 384 threads
    __shared__ float Y[ND][RK + 1];
    __shared__ float u[ND];
    __shared__ float red[ND];
    __shared__ float red6[8];
    __shared__ float sarr[RK];

    for (int j = 0; j < RK; j++) Y[t][j] = xx[(long)t * SSTR + b * RK + j];
    __syncthreads();

    // modified Gram-Schmidt (row-local updates)
    for (int j = 0; j < RK; j++) {
        float nv = blockSum384(Y[t][j] * Y[t][j], red6, t);
        float inv = (nv > 1e-30f) ? 1.f / sqrtf(nv) : 0.f;
        Y[t][j] *= inv;
        for (int l = j + 1; l < RK; l++) {
            float dt = blockSum384(Y[t][j] * Y[t][l], red6, t);
            Y[t][l] -= dt * Y[t][j];
        }
    }
    __syncthreads();

    const float* A = Gall + (long)b * ND * ND;
    const float* tau = tauA + b * ND;
    const int col = t % RK;       // 384 = 16*24
    const int sl = t / RK;
    for (int k = ND - 3; k >= 0; k--) {
        int m = ND - 1 - k;
        // reflector now lives in ROW k (columns k+1..) -> coalesced load
        for (int i = t; i < m; i += 384) u[i] = A[(long)k * ND + (k + 1 + i)];
        float tk = tau[k];
        __syncthreads();
        float p = 0.f;
        for (int i = sl; i < m; i += 16) p += u[i] * Y[k + 1 + i][col];
        red[col * 16 + sl] = p; __syncthreads();
        if (sl == 0) {
            float ssum = 0.f;
            for (int q = 0; q < 16; q++) ssum += red[col * 16 + q];
            sarr[col] = tk * ssum;
        }
        __syncthreads();
        float sv = sarr[col];
        for (int i = sl; i < m; i += 16) Y[k + 1 + i][col] -= u[i] * sv;
        __syncthreads();
    }
    for (int l = t; l < ND * RK; l += 384) {
        int i = l / RK, j = l - i * RK;
        Qout[(long)b * ND * RK + l] = Y[i][j];
    }
}

// ---------------- Sp = X_w @ Q ----------------
__global__ __launch_bounds__(256)
void proj_kernel(const float* __restrict__ Xw, const float* __restrict__ Qall,
                 float* __restrict__ P)
{
    int b = blockIdx.y;
    int r0 = blockIdx.x * 256;
    __shared__ float Qs[ND][RK + 1];
    const float* Q = Qall + (long)b * ND * RK;
    for (int l = threadIdx.x; l < ND * RK; l += 256) {
        int i = l / RK, j = l - i * RK;
        Qs[i][j] = Q[l];
    }
    __syncthreads();
    int r = r0 + threadIdx.x;
    const float* X = Xw + (long)b * NR * ND + (long)r * ND;
    float acc[RK];
#pragma unroll
    for (int j = 0; j < RK; j++) acc[j] = 0.f;
    for (int k = 0; k < ND; k++) {
        float xv = X[k];
#pragma unroll
        for (int j = 0; j < RK; j++) acc[j] += xv * Qs[k][j];
    }
    float* Pr = P + (long)b * NR * RK + (long)r * RK;
#pragma unroll
    for (int j = 0; j < RK; j++) Pr[j] = acc[j];
}

// ---------------- M = Sp^T Tp ; R = polar(M) via Newton-Schulz ; write R - I ----------------
__global__ __launch_bounds__(256)
void polar_kernel(const float* __restrict__ Sp, const float* __restrict__ Tp,
                  float* __restrict__ RmI)
{
    int b = blockIdx.x, t = threadIdx.x;
    __shared__ float Sb[128][RK + 1], Tb[128][RK + 1];
    __shared__ float Xm[RK][RK + 1], Bm[RK][RK + 1], Mm[RK][RK + 1];
    __shared__ float red[256];

    float accM[3] = {0.f, 0.f, 0.f};
    for (int c = 0; c < 4; c++) {
        for (int l = t; l < 128 * RK; l += 256) {
            int row = l / RK, colj = l - row * RK;
            Sb[row][colj] = Sp[(long)b * NR * RK + (long)(c * 128 + row) * RK + colj];
            Tb[row][colj] = Tp[(long)b * NR * RK + (long)(c * 128 + row) * RK + colj];
        }
        __syncthreads();
        for (int q = 0; q < 3; q++) {
            int e = t + q * 256;
            if (e < RK * RK) {
                int r = e / RK, s2 = e - r * RK;
                float a = 0.f;
                for (int n = 0; n < 128; n++) a += Sb[n][r] * Tb[n][s2];
                accM[q] += a;
            }
        }
        __syncthreads();
    }
    float ss = 0.f;
    for (int q = 0; q < 3; q++) {
        int e = t + q * 256;
        if (e < RK * RK) {
            int r = e / RK, s2 = e - r * RK;
            Mm[r][s2] = accM[q];
            ss += accM[q] * accM[q];
        }
    }
    red[t] = ss; __syncthreads();
    for (int off = 128; off > 0; off >>= 1) {
        if (t < off) red[t] += red[t + off];
        __syncthreads();
    }
    float fro = sqrtf(red[0]);
    float inv = (fro > 1e-30f) ? 1.f / fro : 0.f;
    for (int q = 0; q < 3; q++) {
        int e = t + q * 256;
        if (e < RK * RK) { int r = e / RK, s2 = e - r * RK; Xm[r][s2] = Mm[r][s2] * inv; }
    }
    __syncthreads();
    for (int it = 0; it < POLAR_ITERS; it++) {
        // B = X^T X
        for (int q = 0; q < 3; q++) {
            int e = t + q * 256;
            if (e < RK * RK) {
                int r = e / RK, s2 = e - r * RK;
                float a = 0.f;
                for (int k = 0; k < RK; k++) a += Xm[k][r] * Xm[k][s2];
                Bm[r][s2] = a;
            }
        }
        __syncthreads();
        // Xn = 1.5 X - 0.5 X B
        for (int q = 0; q < 3; q++) {
            int e = t + q * 256;
            if (e < RK * RK) {
                int r = e / RK, s2 = e - r * RK;
                float a = 0.f;
                for (int k = 0; k < RK; k++) a += Xm[r][k] * Bm[k][s2];
                Mm[r][s2] = 1.5f * Xm[r][s2] - 0.5f * a;
            }
        }
        __syncthreads();
        for (int q = 0; q < 3; q++) {
            int e = t + q * 256;
            if (e < RK * RK) { int r = e / RK, s2 = e - r * RK; Xm[r][s2] = Mm[r][s2]; }
        }
        __syncthreads();
    }
    for (int q = 0; q < 3; q++) {
        int e = t + q * 256;
        if (e < RK * RK) {
            int r = e / RK, s2 = e - r * RK;
            RmI[(long)b * RK * RK + e] = Xm[r][s2] - ((r == s2) ? 1.f : 0.f);
        }
    }
}

// ---------------- aligned = S_w + Sp (R-I) Q^T  (writes d_out) ----------------
__global__ __launch_bounds__(256)
void align_kernel(const float* __restrict__ Sw, const float* __restrict__ Sp,
                  const float* __restrict__ RmI, const float* __restrict__ Qall,
                  float* __restrict__ out)
{
    int b = blockIdx.y;
    int r0 = blockIdx.x * 64;
    int t = threadIdx.x;
    __shared__ float Qs[ND][RK + 1];
    __shared__ float Rm[RK][RK + 1];
    __shared__ float Ss[64][RK + 1];
    __shared__ float W[64][RK + 1];

    for (int l = t; l < ND * RK; l += 256) {
        int i = l / RK, j = l - i * RK;
        Qs[i][j] = Qall[(long)b * ND * RK + l];
    }
    for (int l = t; l < RK * RK; l += 256) {
        int i = l / RK, j = l - i * RK;
        Rm[i][j] = RmI[(long)b * RK * RK + l];
    }
    for (int l = t; l < 64 * RK; l += 256) {
        int i = l / RK, j = l - i * RK;
        Ss[i][j] = Sp[(long)b * NR * RK + (long)(r0 + i) * RK + j];
    }
    __syncthreads();
    for (int l = t; l < 64 * RK; l += 256) {
        int r = l / RK, j = l - r * RK;
        float a = 0.f;
        for (int k = 0; k < RK; k++) a += Ss[r][k] * Rm[k][j];
        W[r][j] = a;
    }
    __syncthreads();
    for (int r = 0; r < 64; r++) {
        for (int c = t; c < ND; c += 256) {
            float a = Sw[(long)b * NR * ND + (long)(r0 + r) * ND + c];
            float s2 = 0.f;
#pragma unroll
            for (int j = 0; j < RK; j++) s2 += W[r][j] * Qs[c][j];
            out[(long)b * NR * ND + (long)(r0 + r) * ND + c] = a + s2;
        }
    }
}

// ---------------- mean cosine ----------------
__global__ __launch_bounds__(256)
void cos_kernel(const float* __restrict__ out, const float* __restrict__ tgt,
                float* __restrict__ acc)
{
    int row = blockIdx.x * 4 + (threadIdx.x >> 6);
    int lane = threadIdx.x & 63;
    const float* a = out + (long)row * ND;
    const float* tg = tgt + (long)row * ND;
    float sd = 0.f, sa = 0.f, st = 0.f;
    for (int i = lane; i < ND; i += 64) {
        float av = a[i], tv = tg[i];
        sd += av * tv; sa += av * av; st += tv * tv;
    }
#pragma unroll
    for (int off = 32; off > 0; off >>= 1) {
        sd += __shfl_down(sd, off); sa += __shfl_down(sa, off); st += __shfl_down(st, off);
    }
    __shared__ float part[4];
    if (lane == 0) part[threadIdx.x >> 6] = sd / (sqrtf(sa) * sqrtf(st) + 1e-8f);
    __syncthreads();
    if (threadIdx.x == 0) atomicAdd(acc, part[0] + part[1] + part[2] + part[3]);
}

__global__ void finalize_kernel(const float* __restrict__ acc, float* __restrict__ out)
{
    out[0] = acc[0] / 32768.0f;
}

// ---------------- host ----------------
static inline void launch_gemm(int TA, const float* A, const float* Bm, float* C,
                               int M, int N, int K, long sA, long sB, long sC,
                               int lda, int ldb, int ldc, int mode,
                               const float* scale, hipStream_t stream)
{
    dim3 grid((M / 64) * (N / 64), BATCH);
    if (TA)
        gemm_kernel<1><<<grid, dim3(256), 0, stream>>>(A, Bm, C, M, N, K, sA, sB, sC, lda, ldb, ldc, mode, scale);
    else
        gemm_kernel<0><<<grid, dim3(256), 0, stream>>>(A, Bm, C, M, N, K, sA, sB, sC, lda, ldb, ldc, mode, scale);
}

extern "C" void kernel_launch(void* const* d_in, const int* in_sizes, int n_in,
                              void* d_out, int out_size, void* d_ws, size_t ws_size,
                              hipStream_t stream)
{
    const float* src = (const float*)d_in[0];
    const float* tgt = (const float*)d_in[1];
    float* out = (float*)d_out;
    float* ws = (float*)d_ws;

    // workspace layout (floats); requires ~189 MB of ws
    float* A0 = ws;
    float* A1 = ws + 1 * SZC;
    float* A2 = ws + 2 * SZC;
    float* A3 = ws + 3 * SZC;
    float* A4 = ws + 4 * SZC;
    float* S5 = ws + 5 * SZC;
    float* nrm_s = S5;
    float* nrm_t = S5 + 64;
    float* dd = S5 + 128;
    float* ee = dd + BATCH * ND;
    float* tt = ee + BATCH * ND;
    float* lam = tt + BATCH * ND;
    float* accp = lam + BATCH * RK;

    float* Tm = out;                 // transient NS "T" buffer lives in d_out
    float* SW = A0;                  // 512x384 per batch (spans A0..A1)
    float* TW = A0 + (long)BATCH * NR * ND;   // spans into A2 region
    float* G  = A3;
    // C-region in A4:
    float* scr = A4;                                   // 6 * 384 * 1536
    float* Qp  = A4 + 6L * ND * SSTR;
    float* Spp = Qp + (long)BATCH * ND * RK;
    float* Tpp = Spp + (long)BATCH * NR * RK;
    float* Rp  = Tpp + (long)BATCH * NR * RK;
    float* yarr = scr + 5L * ND * SSTR;

    const long sXin = (long)NR * ND;     // 196608
    const long sSq  = (long)ND * ND;     // 147456

    // ---- phase S: covariance + Newton-Schulz inverse sqrt ----
    launch_gemm(1, src, src, A0, ND, ND, NR, sXin, sXin, sSq, ND, ND, ND, MODE_COV, nullptr, stream);
    frob_kernel<<<BATCH, 256, 0, stream>>>(A0, nrm_s);
    init_kernel<<<dim3(4096), 256, 0, stream>>>(A0, A2, nrm_s);
    {
        float* Y = A0; float* Yo = A1; float* Z = A2; float* Zo = A3;
        for (int it = 0; it < NSI; it++) {
            launch_gemm(0, Z, Y, Tm, ND, ND, ND, sSq, sSq, sSq, ND, ND, ND, MODE_NST, nullptr, stream);
            launch_gemm(0, Y, Tm, Yo, ND, ND, ND, sSq, sSq, sSq, ND, ND, ND, MODE_PLAIN, nullptr, stream);
            launch_gemm(0, Tm, Z, Zo, ND, ND, ND, sSq, sSq, sSq, ND, ND, ND, MODE_PLAIN, nullptr, stream);
            float* tmp = Y; Y = Yo; Yo = tmp;
            tmp = Z; Z = Zo; Zo = tmp;
        }
        // Z_s ends in A3
    }
    // ---- phase T ----
    launch_gemm(1, tgt, tgt, A0, ND, ND, NR, sXin, sXin, sSq, ND, ND, ND, MODE_COV, nullptr, stream);
    frob_kernel<<<BATCH, 256, 0, stream>>>(A0, nrm_t);
    init_kernel<<<dim3(4096), 256, 0, stream>>>(A0, A2, nrm_t);
    {
        float* Y = A0; float* Yo = A1; float* Z = A2; float* Zo = A4;
        for (int it = 0; it < NSI; it++) {
            launch_gemm(0, Z, Y, Tm, ND, ND, ND, sSq, sSq, sSq, ND, ND, ND, MODE_NST, nullptr, stream);
            launch_gemm(0, Y, Tm, Yo, ND, ND, ND, sSq, sSq, sSq, ND, ND, ND, MODE_PLAIN, nullptr, stream);
            launch_gemm(0, Tm, Z, Zo, ND, ND, ND, sSq, sSq, sSq, ND, ND, ND, MODE_PLAIN, nullptr, stream);
            float* tmp = Y; Y = Yo; Yo = tmp;
            tmp = Z; Z = Zo; Zo = tmp;
        }
        // Z_t ends in A4
    }
    // ---- whiten: S_w = S Z_s / sqrt(nrm), T_w = T Z_t / sqrt(nrm) ----
    launch_gemm(0, src, A3, SW, NR, ND, ND, sXin, sSq, sXin, ND, ND, ND, MODE_SCALE, nrm_s, stream);
    launch_gemm(0, tgt, A4, TW, NR, ND, ND, sXin, sSq, sXin, ND, ND, ND, MODE_SCALE, nrm_t, stream);
    // ---- G = S_w^T S_w + T_w^T T_w ----
    launch_gemm(1, SW, SW, G, ND, ND, NR, sXin, sXin, sSq, ND, ND, ND, MODE_PLAIN, nullptr, stream);
    launch_gemm(1, TW, TW, G, ND, ND, NR, sXin, sXin, sSq, ND, ND, ND, MODE_ACC, nullptr, stream);
    // ---- eigensolver: tridiag + bisection + inverse iteration + back-transform ----
    tridiag_kernel<<<BATCH, 384, 0, stream>>>(G, dd, ee, tt);
    eigvals_kernel<<<BATCH, 64, 0, stream>>>(dd, ee, lam);
    invit_kernel<<<BATCH, 64, 0, stream>>>(dd, ee, lam, scr);
    orthbt_kernel<<<BATCH, 384, 0, stream>>>(yarr, G, tt, Qp);
    // ---- projections, Procrustes, output ----
    proj_kernel<<<dim3(2, BATCH), 256, 0, stream>>>(SW, Qp, Spp);
    proj_kernel<<<dim3(2, BATCH), 256, 0, stream>>>(TW, Qp, Tpp);
    polar_kernel<<<BATCH, 256, 0, stream>>>(Spp, Tpp, Rp);
    align_kernel<<<dim3(8, BATCH), 256, 0, stream>>>(SW, Spp, Rp, Qp, out);
    hipMemsetAsync((void*)accp, 0, 4, stream);
    cos_kernel<<<dim3(8192), 256, 0, stream>>>(out, tgt, accp);
    finalize_kernel<<<1, 1, 0, stream>>>(accp, out + (long)BATCH * NR * ND);
    (void)in_sizes; (void)n_in; (void)out_size; (void)ws_size;
}

// Round 3
// 12543.052 us; speedup vs baseline: 1.5406x; 1.1954x over previous
//
#include <hip/hip_runtime.h>
#include <math.h>

static constexpr int BATCH = 64;
static constexpr int NR  = 512;    // rows per matrix (n)
static constexpr int ND  = 384;    // feature dim (N)
static constexpr int RK  = 24;     // rank
static constexpr int NSI = 5;      // Newton-Schulz iters (whitening)
static constexpr int POLAR_ITERS = 36;
static constexpr long SZC = (long)BATCH * ND * ND;      // 9,437,184 floats
static constexpr int SSTR = BATCH * RK;                 // 1536 (inverse-iter solve stride)

#define MODE_PLAIN 0
#define MODE_COV   1
#define MODE_NST   2
#define MODE_SCALE 3
#define MODE_ACC   4

// ---------------- generic batched tiled SGEMM (128x128 tile, 8x8 microtile) ----
// TA=0: C = A(MxK,row-major) * B(KxN,row-major)
// TA=1: C = A^T * B, A stored KxM row-major
template<int TA>
__global__ __launch_bounds__(256)
void gemm_kernel(const float* __restrict__ Ag, const float* __restrict__ Bg,
                 float* __restrict__ Cg, int M, int N, int K,
                 long sA, long sB, long sC, int lda, int ldb, int ldc,
                 int mode, const float* __restrict__ scale)
{
    const int batch = blockIdx.y;
    const int tilesN = N >> 7;            // N/128
    const int tx = blockIdx.x % tilesN;
    const int ty = blockIdx.x / tilesN;
    const int n0 = tx * 128, m0 = ty * 128;
    const float* A = Ag + (long)batch * sA;
    const float* Bm = Bg + (long)batch * sB;
    float* C = Cg + (long)batch * sC;

    __shared__ float As[16][132];
    __shared__ float Bs[16][132];

    const int tid = threadIdx.x;
    const int tr = tid >> 4, tc = tid & 15;   // 16x16 thread grid

    float acc[8][8];
#pragma unroll
    for (int i = 0; i < 8; i++)
#pragma unroll
        for (int j = 0; j < 8; j++) acc[i][j] = 0.f;

    for (int k0 = 0; k0 < K; k0 += 16) {
        // ---- stage A tile ----
        if (TA) {
            // A^T: element (kk, m) = A[(k0+kk)*lda + m0+m]; straight [kk][m] copy
#pragma unroll
            for (int q = 0; q < 2; q++) {
                int idx = tid + q * 256;          // 512 float4s
                int kk = idx >> 5, mq = (idx & 31) * 4;
                float4 av = *(const float4*)&A[(long)(k0 + kk) * lda + m0 + mq];
                *(float4*)&As[kk][mq] = av;
            }
        } else {
            // A: element (m, kk) = A[(m0+m)*lda + k0+kk]; transpose on LDS store
#pragma unroll
            for (int q = 0; q < 2; q++) {
                int idx = tid + q * 256;          // 512 float4s
                int mrow = idx >> 2, kq = (idx & 3) * 4;
                float4 av = *(const float4*)&A[(long)(m0 + mrow) * lda + k0 + kq];
                As[kq + 0][mrow] = av.x;
                As[kq + 1][mrow] = av.y;
                As[kq + 2][mrow] = av.z;
                As[kq + 3][mrow] = av.w;
            }
        }
        // ---- stage B tile (straight copy) ----
#pragma unroll
        for (int q = 0; q < 2; q++) {
            int idx = tid + q * 256;
            int kk = idx >> 5, nq = (idx & 31) * 4;
            float4 bv = *(const float4*)&Bm[(long)(k0 + kk) * ldb + n0 + nq];
            *(float4*)&Bs[kk][nq] = bv;
        }
        __syncthreads();

#pragma unroll
        for (int kk = 0; kk < 16; kk++) {
            float4 a0 = *(const float4*)&As[kk][tr * 4];
            float4 a1 = *(const float4*)&As[kk][tr * 4 + 64];
            float4 b0 = *(const float4*)&Bs[kk][tc * 4];
            float4 b1 = *(const float4*)&Bs[kk][tc * 4 + 64];
            float av[8] = {a0.x, a0.y, a0.z, a0.w, a1.x, a1.y, a1.z, a1.w};
            float bv[8] = {b0.x, b0.y, b0.z, b0.w, b1.x, b1.y, b1.z, b1.w};
#pragma unroll
            for (int i = 0; i < 8; i++)
#pragma unroll
                for (int j = 0; j < 8; j++) acc[i][j] += av[i] * bv[j];
        }
        __syncthreads();
    }

    float scl = 1.f;
    if (mode == MODE_SCALE) scl = 1.0f / sqrtf(scale[batch]);

#pragma unroll
    for (int ih = 0; ih < 2; ih++) {
#pragma unroll
        for (int ii = 0; ii < 4; ii++) {
            int gm = m0 + ih * 64 + tr * 4 + ii;
#pragma unroll
            for (int jh = 0; jh < 2; jh++) {
                int gn0 = n0 + jh * 64 + tc * 4;
                float* crow = C + (long)gm * ldc + gn0;
                float4 old;
                if (mode == MODE_ACC) old = *(const float4*)crow;
                float vout[4];
#pragma unroll
                for (int jj = 0; jj < 4; jj++) {
                    int gn = gn0 + jj;
                    float v = acc[ih * 4 + ii][jh * 4 + jj];
                    if (mode == MODE_COV)      v = v * (1.0f / 512.0f) + ((gm == gn) ? 1e-5f : 0.f);
                    else if (mode == MODE_NST) v = ((gm == gn) ? 1.5f : 0.f) - 0.5f * v;
                    else if (mode == MODE_SCALE) v *= scl;
                    vout[jj] = v;
                }
                if (mode == MODE_ACC) {
                    vout[0] += old.x; vout[1] += old.y; vout[2] += old.z; vout[3] += old.w;
                }
                float4 st = {vout[0], vout[1], vout[2], vout[3]};
                *(float4*)crow = st;
            }
        }
    }
}

// ---------------- Frobenius norm per batch ----------------
__global__ __launch_bounds__(256)
void frob_kernel(const float* __restrict__ Cm, float* __restrict__ nrm)
{
    int b = blockIdx.x;
    const float* p = Cm + (long)b * ND * ND;
    float s = 0.f;
    for (int i = threadIdx.x; i < ND * ND; i += 256) { float v = p[i]; s += v * v; }
    __shared__ float red[256];
    red[threadIdx.x] = s; __syncthreads();
    for (int off = 128; off > 0; off >>= 1) {
        if (threadIdx.x < off) red[threadIdx.x] += red[threadIdx.x + off];
        __syncthreads();
    }
    if (threadIdx.x == 0) nrm[b] = sqrtf(red[0]);
}

// ---------------- Y0 = C/normC (in place), Z0 = I ----------------
__global__ __launch_bounds__(256)
void init_kernel(float* __restrict__ Y, float* __restrict__ Z, const float* __restrict__ nrm)
{
    const int total = BATCH * ND * ND;
    for (int idx = blockIdx.x * 256 + threadIdx.x; idx < total; idx += gridDim.x * 256) {
        int b = idx / (ND * ND);
        int rem = idx - b * (ND * ND);
        int r = rem / ND, c = rem - r * ND;
        Y[idx] = Y[idx] / nrm[b];
        Z[idx] = (r == c) ? 1.f : 0.f;
    }
}

// ---------------- block reduction over 768 threads ----------------
__device__ __forceinline__ float bred768(float v, float* red12, int t)
{
#pragma unroll
    for (int off = 32; off > 0; off >>= 1) v += __shfl_down(v, off);
    if ((t & 63) == 0) red12[t >> 6] = v;
    __syncthreads();
    float r = 0.f;
#pragma unroll
    for (int i = 0; i < 12; i++) r += red12[i];
    __syncthreads();
    return r;
}

// ---------------- Householder tridiagonalization ----------------
// 768 threads: (h, c) with h = row-half, c = column. Matvec and rank-2 update
// each split their i-range in half -> chain length m/2, 12 waves/CU.
// Reflector u_k stored into row k (coalesced); consumed by orthbt_kernel.
__global__ __launch_bounds__(768)
void tridiag_kernel(float* __restrict__ Gall, float* __restrict__ dA,
                    float* __restrict__ eA, float* __restrict__ tauA)
{
    int b = blockIdx.x;
    float* A = Gall + (long)b * ND * ND;
    float* d = dA + b * ND; float* e = eA + b * ND; float* tau = tauA + b * ND;
    const int t = threadIdx.x;
    const int h = (t >= ND) ? 1 : 0;
    const int c = t - h * ND;            // 0..383
    __shared__ float u_s[ND], w_s[ND];
    __shared__ float pp[2][ND];
    __shared__ float red12[12];
    __shared__ float s_tau;

    for (int k = 0; k <= ND - 3; k++) {
        const int m = ND - 1 - k;
        float* rowk = A + (long)k * ND + (k + 1);
        float v = 0.f;
        if (!h && c < m) { v = rowk[c]; u_s[c] = v; }
        float sigma = bred768(v * v, red12, t);   // syncs inside; u_s visible after
        if (t == 0) {
            float v0 = u_s[0];
            float normx = sqrtf(sigma);
            float alpha = (v0 >= 0.f) ? -normx : normx;
            float denom = sigma - alpha * v0;
            float tk = (denom > 1e-30f) ? 1.f / denom : 0.f;   // tau = 2/||u||^2
            s_tau = tk;
            e[k] = alpha; tau[k] = tk; d[k] = A[(long)k * ND + k];
            u_s[0] = v0 - alpha;
        }
        __syncthreads();
        const float tk = s_tau;

        const int mh = m >> 1;
        const int i0 = h ? mh : 0;
        const int i1 = h ? m : mh;

        // partial matvec: pp[h][c] = sum_{i in half} A[k+1+i][k+1+c] * u[i]
        float p = 0.f;
        if (c < m) {
            const float* col = A + (long)(k + 1) * ND + (k + 1) + c;
            int i = i0;
            for (; i + 4 <= i1; i += 4) {
                p += col[(long)(i    ) * ND] * u_s[i]
                   + col[(long)(i + 1) * ND] * u_s[i + 1]
                   + col[(long)(i + 2) * ND] * u_s[i + 2]
                   + col[(long)(i + 3) * ND] * u_s[i + 3];
            }
            for (; i < i1; i++) p += col[(long)i * ND] * u_s[i];
        }
        pp[h][c] = p;
        __syncthreads();

        float contrib = 0.f;
        float pc = 0.f;
        if (!h && c < m) {
            pc = tk * (pp[0][c] + pp[1][c]);
            contrib = u_s[c] * pc;
        }
        float dotup = bred768(contrib, red12, t);
        float sc = 0.5f * tk * dotup;
        if (!h && c < m) w_s[c] = pc - sc * u_s[c];
        __syncthreads();

        // rank-2 update: rows [i0,i1) of column c (disjoint between halves)
        if (c < m) {
            const float uc = u_s[c], wc = w_s[c];
            float* col = A + (long)(k + 1) * ND + (k + 1) + c;
            int i = i0;
            for (; i + 2 <= i1; i += 2) {
                float a0 = col[(long)(i    ) * ND] - (u_s[i    ] * wc + w_s[i    ] * uc);
                float a1 = col[(long)(i + 1) * ND] - (u_s[i + 1] * wc + w_s[i + 1] * uc);
                col[(long)(i    ) * ND] = a0;
                col[(long)(i + 1) * ND] = a1;
            }
            for (; i < i1; i++) col[(long)i * ND] -= (u_s[i] * wc + w_s[i] * uc);
            if (!h) rowk[c] = uc;   // store reflector into row k (coalesced)
        }
        __syncthreads();
    }
    if (t == 0) {
        d[ND - 2] = A[(long)(ND - 2) * ND + (ND - 2)];
        d[ND - 1] = A[(long)(ND - 1) * ND + (ND - 1)];
        e[ND - 2] = A[(long)(ND - 2) * ND + (ND - 1)];
        e[ND - 1] = 0.f; tau[ND - 2] = 0.f; tau[ND - 1] = 0.f;
    }
}

// ---------------- Sturm bisection: top-24 eigenvalues ----------------
__global__ __launch_bounds__(64)
void eigvals_kernel(const float* __restrict__ dA, const float* __restrict__ eA,
                    float* __restrict__ lamA)
{
    int b = blockIdx.x, t = threadIdx.x;   // 64 threads
    __shared__ float d[ND], e2[ND], ea[ND], red[64];
    for (int i = t; i < ND; i += 64) {
        d[i] = dA[b * ND + i];
        float ev = eA[b * ND + i];
        ea[i] = fabsf(ev); e2[i] = ev * ev;
    }
    __syncthreads();
    float lo = 1e30f, hi = -1e30f;
    for (int i = t; i < ND; i += 64) {
        float r = ea[i] + ((i > 0) ? ea[i - 1] : 0.f);
        lo = fminf(lo, d[i] - r); hi = fmaxf(hi, d[i] + r);
    }
    red[t] = lo; __syncthreads();
    for (int off = 32; off > 0; off >>= 1) {
        if (t < off) red[t] = fminf(red[t], red[t + off]);
        __syncthreads();
    }
    lo = red[0]; __syncthreads();
    red[t] = hi; __syncthreads();
    for (int off = 32; off > 0; off >>= 1) {
        if (t < off) red[t] = fmaxf(red[t], red[t + off]);
        __syncthreads();
    }
    hi = red[0];
    if (t < RK) {
        int idx = ND - 1 - t;          // ascending index (t=0 -> largest)
        float a = lo, c = hi;
        for (int it = 0; it < 42; it++) {
            float mid = 0.5f * (a + c);
            int cnt = 0;
            float q = d[0] - mid;
            if (q < 0.f) cnt++;
            for (int i = 1; i < ND; i++) {
                float den = q;
                if (fabsf(den) < 1e-25f) den = (den < 0.f) ? -1e-25f : 1e-25f;
                q = d[i] - mid - e2[i - 1] / den;
                if (q < 0.f) cnt++;
            }
            if (cnt > idx) c = mid; else a = mid;
        }
        lamA[b * RK + t] = 0.5f * (a + c);
    }
}

// ---------------- tridiagonal inverse iteration (pivoted LU) ----------------
__global__ __launch_bounds__(64)
void invit_kernel(const float* __restrict__ dA, const float* __restrict__ eA,
                  const float* __restrict__ lamA, float* __restrict__ scr)
{
    int b = blockIdx.x, t = threadIdx.x;
    __shared__ float d[ND], e[ND];
    for (int i = t; i < ND; i += 64) { d[i] = dA[b * ND + i]; e[i] = eA[b * ND + i]; }
    __syncthreads();
    if (t >= RK) return;
    const int s = b * RK + t;
    float* ua = scr;
    float* ub = scr + (long)ND * SSTR;
    float* uc = scr + 2L * ND * SSTR;
    float* ul = scr + 3L * ND * SSTR;
    float* up = scr + 4L * ND * SSTR;
    float* y  = scr + 5L * ND * SSTR;
    float lam = lamA[s];
    // factor T - lam*I with partial pivoting (slagtf-style)
    float ai = d[0] - lam;
    float bc = e[0];
    for (int i = 0; i < ND - 1; i++) {
        float sub = e[i];
        float dn = d[i + 1] - lam;
        float en = (i + 1 < ND - 1) ? e[i + 1] : 0.f;
        long o = (long)i * SSTR + s;
        if (fabsf(ai) >= fabsf(sub)) {
            float aa = (ai == 0.f) ? 1e-20f : ai;
            float mlt = sub / aa;
            ua[o] = aa; ub[o] = bc; uc[o] = 0.f; ul[o] = mlt; up[o] = 0.f;
            ai = dn - mlt * bc;
            bc = en;
        } else {
            float mlt = ai / sub;
            ua[o] = sub; ub[o] = dn; uc[o] = en; ul[o] = mlt; up[o] = 1.f;
            ai = bc - mlt * dn;
            bc = -mlt * en;
        }
    }
    { long o = (long)(ND - 1) * SSTR + s; ua[o] = (ai == 0.f) ? 1e-20f : ai; ub[o] = 0.f; uc[o] = 0.f; }

    for (int pass = 0; pass < 2; pass++) {
        if (pass == 0) {
            for (int i = 0; i < ND; i++) {
                unsigned h = ((unsigned)i * 1103515245u) ^ ((unsigned)s * 747796405u);
                h *= 2654435769u; h ^= h >> 16;
                y[(long)i * SSTR + s] = ((float)(h & 0xFFFFu) * (1.f / 65536.f)) - 0.5f;
            }
        }
        // forward substitution with pivot replay
        for (int i = 0; i < ND - 1; i++) {
            long o = (long)i * SSTR + s, o1 = o + SSTR;
            float yi = y[o], y1 = y[o1];
            if (up[o] == 0.f) { y[o1] = y1 - ul[o] * yi; }
            else { y[o] = y1; y[o1] = yi - ul[o] * y1; }
        }
        // back substitution (two superdiagonals)
        {
            long oN = (long)(ND - 1) * SSTR + s;
            float xN = y[oN] / ua[oN]; y[oN] = xN;
            long o = oN - SSTR;
            float x1 = xN, x2 = 0.f;
            float xm = (y[o] - ub[o] * x1) / ua[o]; y[o] = xm; x2 = x1; x1 = xm;
            for (int i = ND - 3; i >= 0; i--) {
                o -= SSTR;
                float xi = (y[o] - ub[o] * x1 - uc[o] * x2) / ua[o];
                y[o] = xi; x2 = x1; x1 = xi;
            }
        }
        float nn = 0.f;
        for (int i = 0; i < ND; i++) { float v = y[(long)i * SSTR + s]; nn += v * v; }
        float inv = (nn > 0.f) ? 1.f / sqrtf(nn) : 0.f;
        for (int i = 0; i < ND; i++) y[(long)i * SSTR + s] *= inv;
    }
}

// ---------------- MGS + Householder back-transform (one WG per batch) ----------------
__device__ __forceinline__ float blockSum384(float v, float* red6, int t)
{
#pragma unroll
    for (int off = 32; off > 0; off >>= 1) v += __shfl_down(v, off);
    __syncthreads();
    if ((t & 63) == 0) red6[t >> 6] = v;
    __syncthreads();
    return red6[0] + red6[1] + red6[2] + red6[3] + red6[4] + red6[5];
}

__global__ __launch_bounds__(384)
void orthbt_kernel(const float* __restrict__ xx, const float* __restrict__ Gall,
                   const float* __restrict__ tauA, float* __restrict__ Qout)
{
    int b = blockIdx.x, t = threadIdx.x;   // 384 threads
    __shared__ float Y[ND][RK + 1];
    __shared__ float u[ND];
    __shared__ float red[ND];
    __shared__ float red6[8];
    __shared__ float sarr[RK];

    for (int j = 0; j < RK; j++) Y[t][j] = xx[(long)t * SSTR + b * RK + j];
    __syncthreads();

    // modified Gram-Schmidt (row-local updates)
    for (int j = 0; j < RK; j++) {
        float nv = blockSum384(Y[t][j] * Y[t][j], red6, t);
        float inv = (nv > 1e-30f) ? 1.f / sqrtf(nv) : 0.f;
        Y[t][j] *= inv;
        for (int l = j + 1; l < RK; l++) {
            float dt = blockSum384(Y[t][j] * Y[t][l], red6, t);
            Y[t][l] -= dt * Y[t][j];
        }
    }
    __syncthreads();

    const float* A = Gall + (long)b * ND * ND;
    const float* tau = tauA + b * ND;
    const int col = t % RK;       // 384 = 16*24
    const int sl = t / RK;
    for (int k = ND - 3; k >= 0; k--) {
        int m = ND - 1 - k;
        // reflector lives in ROW k (columns k+1..) -> coalesced load
        for (int i = t; i < m; i += 384) u[i] = A[(long)k * ND + (k + 1 + i)];
        float tk = tau[k];
        __syncthreads();
        float p = 0.f;
        for (int i = sl; i < m; i += 16) p += u[i] * Y[k + 1 + i][col];
        red[col * 16 + sl] = p; __syncthreads();
        if (sl == 0) {
            float ssum = 0.f;
            for (int q = 0; q < 16; q++) ssum += red[col * 16 + q];
            sarr[col] = tk * ssum;
        }
        __syncthreads();
        float sv = sarr[col];
        for (int i = sl; i < m; i += 16) Y[k + 1 + i][col] -= u[i] * sv;
        __syncthreads();
    }
    for (int l = t; l < ND * RK; l += 384) {
        int i = l / RK, j = l - i * RK;
        Qout[(long)b * ND * RK + l] = Y[i][j];
    }
}

// ---------------- Sp = X_w @ Q ----------------
__global__ __launch_bounds__(256)
void proj_kernel(const float* __restrict__ Xw, const float* __restrict__ Qall,
                 float* __restrict__ P)
{
    int b = blockIdx.y;
    int r0 = blockIdx.x * 256;
    __shared__ float Qs[ND][RK + 1];
    const float* Q = Qall + (long)b * ND * RK;
    for (int l = threadIdx.x; l < ND * RK; l += 256) {
        int i = l / RK, j = l - i * RK;
        Qs[i][j] = Q[l];
    }
    __syncthreads();
    int r = r0 + threadIdx.x;
    const float* X = Xw + (long)b * NR * ND + (long)r * ND;
    float acc[RK];
#pragma unroll
    for (int j = 0; j < RK; j++) acc[j] = 0.f;
    for (int k = 0; k < ND; k++) {
        float xv = X[k];
#pragma unroll
        for (int j = 0; j < RK; j++) acc[j] += xv * Qs[k][j];
    }
    float* Pr = P + (long)b * NR * RK + (long)r * RK;
#pragma unroll
    for (int j = 0; j < RK; j++) Pr[j] = acc[j];
}

// ---------------- M = Sp^T Tp ; R = polar(M) via Newton-Schulz ; write R - I ----------------
__global__ __launch_bounds__(256)
void polar_kernel(const float* __restrict__ Sp, const float* __restrict__ Tp,
                  float* __restrict__ RmI)
{
    int b = blockIdx.x, t = threadIdx.x;
    __shared__ float Sb[128][RK + 1], Tb[128][RK + 1];
    __shared__ float Xm[RK][RK + 1], Bm[RK][RK + 1], Mm[RK][RK + 1];
    __shared__ float red[256];

    float accM[3] = {0.f, 0.f, 0.f};
    for (int c = 0; c < 4; c++) {
        for (int l = t; l < 128 * RK; l += 256) {
            int row = l / RK, colj = l - row * RK;
            Sb[row][colj] = Sp[(long)b * NR * RK + (long)(c * 128 + row) * RK + colj];
            Tb[row][colj] = Tp[(long)b * NR * RK + (long)(c * 128 + row) * RK + colj];
        }
        __syncthreads();
        for (int q = 0; q < 3; q++) {
            int e = t + q * 256;
            if (e < RK * RK) {
                int r = e / RK, s2 = e - r * RK;
                float a = 0.f;
                for (int n = 0; n < 128; n++) a += Sb[n][r] * Tb[n][s2];
                accM[q] += a;
            }
        }
        __syncthreads();
    }
    float ss = 0.f;
    for (int q = 0; q < 3; q++) {
        int e = t + q * 256;
        if (e < RK * RK) {
            int r = e / RK, s2 = e - r * RK;
            Mm[r][s2] = accM[q];
            ss += accM[q] * accM[q];
        }
    }
    red[t] = ss; __syncthreads();
    for (int off = 128; off > 0; off >>= 1) {
        if (t < off) red[t] += red[t + off];
        __syncthreads();
    }
    float fro = sqrtf(red[0]);
    float inv = (fro > 1e-30f) ? 1.f / fro : 0.f;
    for (int q = 0; q < 3; q++) {
        int e = t + q * 256;
        if (e < RK * RK) { int r = e / RK, s2 = e - r * RK; Xm[r][s2] = Mm[r][s2] * inv; }
    }
    __syncthreads();
    for (int it = 0; it < POLAR_ITERS; it++) {
        // B = X^T X
        for (int q = 0; q < 3; q++) {
            int e = t + q * 256;
            if (e < RK * RK) {
                int r = e / RK, s2 = e - r * RK;
                float a = 0.f;
                for (int k = 0; k < RK; k++) a += Xm[k][r] * Xm[k][s2];
                Bm[r][s2] = a;
            }
        }
        __syncthreads();
        // Xn = 1.5 X - 0.5 X B
        for (int q = 0; q < 3; q++) {
            int e = t + q * 256;
            if (e < RK * RK) {
                int r = e / RK, s2 = e - r * RK;
                float a = 0.f;
                for (int k = 0; k < RK; k++) a += Xm[r][k] * Bm[k][s2];
                Mm[r][s2] = 1.5f * Xm[r][s2] - 0.5f * a;
            }
        }
        __syncthreads();
        for (int q = 0; q < 3; q++) {
            int e = t + q * 256;
            if (e < RK * RK) { int r = e / RK, s2 = e - r * RK; Xm[r][s2] = Mm[r][s2]; }
        }
        __syncthreads();
    }
    for (int q = 0; q < 3; q++) {
        int e = t + q * 256;
        if (e < RK * RK) {
            int r = e / RK, s2 = e - r * RK;
            RmI[(long)b * RK * RK + e] = Xm[r][s2] - ((r == s2) ? 1.f : 0.f);
        }
    }
}

// ---------------- aligned = S_w + Sp (R-I) Q^T  (writes d_out) ----------------
__global__ __launch_bounds__(256)
void align_kernel(const float* __restrict__ Sw, const float* __restrict__ Sp,
                  const float* __restrict__ RmI, const float* __restrict__ Qall,
                  float* __restrict__ out)
{
    int b = blockIdx.y;
    int r0 = blockIdx.x * 64;
    int t = threadIdx.x;
    __shared__ float Qs[ND][RK + 1];
    __shared__ float Rm[RK][RK + 1];
    __shared__ float Ss[64][RK + 1];
    __shared__ float W[64][RK + 1];

    for (int l = t; l < ND * RK; l += 256) {
        int i = l / RK, j = l - i * RK;
        Qs[i][j] = Qall[(long)b * ND * RK + l];
    }
    for (int l = t; l < RK * RK; l += 256) {
        int i = l / RK, j = l - i * RK;
        Rm[i][j] = RmI[(long)b * RK * RK + l];
    }
    for (int l = t; l < 64 * RK; l += 256) {
        int i = l / RK, j = l - i * RK;
        Ss[i][j] = Sp[(long)b * NR * RK + (long)(r0 + i) * RK + j];
    }
    __syncthreads();
    for (int l = t; l < 64 * RK; l += 256) {
        int r = l / RK, j = l - r * RK;
        float a = 0.f;
        for (int k = 0; k < RK; k++) a += Ss[r][k] * Rm[k][j];
        W[r][j] = a;
    }
    __syncthreads();
    for (int r = 0; r < 64; r++) {
        for (int c = t; c < ND; c += 256) {
            float a = Sw[(long)b * NR * ND + (long)(r0 + r) * ND + c];
            float s2 = 0.f;
#pragma unroll
            for (int j = 0; j < RK; j++) s2 += W[r][j] * Qs[c][j];
            out[(long)b * NR * ND + (long)(r0 + r) * ND + c] = a + s2;
        }
    }
}

// ---------------- mean cosine ----------------
__global__ __launch_bounds__(256)
void cos_kernel(const float* __restrict__ out, const float* __restrict__ tgt,
                float* __restrict__ acc)
{
    int row = blockIdx.x * 4 + (threadIdx.x >> 6);
    int lane = threadIdx.x & 63;
    const float* a = out + (long)row * ND;
    const float* tg = tgt + (long)row * ND;
    float sd = 0.f, sa = 0.f, st = 0.f;
    for (int i = lane; i < ND; i += 64) {
        float av = a[i], tv = tg[i];
        sd += av * tv; sa += av * av; st += tv * tv;
    }
#pragma unroll
    for (int off = 32; off > 0; off >>= 1) {
        sd += __shfl_down(sd, off); sa += __shfl_down(sa, off); st += __shfl_down(st, off);
    }
    __shared__ float part[4];
    if (lane == 0) part[threadIdx.x >> 6] = sd / (sqrtf(sa) * sqrtf(st) + 1e-8f);
    __syncthreads();
    if (threadIdx.x == 0) atomicAdd(acc, part[0] + part[1] + part[2] + part[3]);
}

__global__ void finalize_kernel(const float* __restrict__ acc, float* __restrict__ out)
{
    out[0] = acc[0] / 32768.0f;
}

// ---------------- host ----------------
static inline void launch_gemm(int TA, const float* A, const float* Bm, float* C,
                               int M, int N, int K, long sA, long sB, long sC,
                               int lda, int ldb, int ldc, int mode,
                               const float* scale, hipStream_t stream)
{
    dim3 grid((M / 128) * (N / 128), BATCH);
    if (TA)
        gemm_kernel<1><<<grid, dim3(256), 0, stream>>>(A, Bm, C, M, N, K, sA, sB, sC, lda, ldb, ldc, mode, scale);
    else
        gemm_kernel<0><<<grid, dim3(256), 0, stream>>>(A, Bm, C, M, N, K, sA, sB, sC, lda, ldb, ldc, mode, scale);
}

extern "C" void kernel_launch(void* const* d_in, const int* in_sizes, int n_in,
                              void* d_out, int out_size, void* d_ws, size_t ws_size,
                              hipStream_t stream)
{
    const float* src = (const float*)d_in[0];
    const float* tgt = (const float*)d_in[1];
    float* out = (float*)d_out;
    float* ws = (float*)d_ws;

    // workspace layout (floats); requires ~189 MB of ws
    float* A0 = ws;
    float* A1 = ws + 1 * SZC;
    float* A2 = ws + 2 * SZC;
    float* A3 = ws + 3 * SZC;
    float* A4 = ws + 4 * SZC;
    float* S5 = ws + 5 * SZC;
    float* nrm_s = S5;
    float* nrm_t = S5 + 64;
    float* dd = S5 + 128;
    float* ee = dd + BATCH * ND;
    float* tt = ee + BATCH * ND;
    float* lam = tt + BATCH * ND;
    float* accp = lam + BATCH * RK;

    float* Tm = out;                 // transient NS "T" buffer lives in d_out
    float* SW = A0;                  // 512x384 per batch (spans A0..A1)
    float* TW = A0 + (long)BATCH * NR * ND;   // spans into A2 region
    float* G  = A3;
    // C-region in A4:
    float* scr = A4;                                   // 6 * 384 * 1536
    float* Qp  = A4 + 6L * ND * SSTR;
    float* Spp = Qp + (long)BATCH * ND * RK;
    float* Tpp = Spp + (long)BATCH * NR * RK;
    float* Rp  = Tpp + (long)BATCH * NR * RK;
    float* yarr = scr + 5L * ND * SSTR;

    const long sXin = (long)NR * ND;     // 196608
    const long sSq  = (long)ND * ND;     // 147456

    // ---- phase S: covariance + Newton-Schulz inverse sqrt ----
    launch_gemm(1, src, src, A0, ND, ND, NR, sXin, sXin, sSq, ND, ND, ND, MODE_COV, nullptr, stream);
    frob_kernel<<<BATCH, 256, 0, stream>>>(A0, nrm_s);
    init_kernel<<<dim3(4096), 256, 0, stream>>>(A0, A2, nrm_s);
    {
        float* Y = A0; float* Yo = A1; float* Z = A2; float* Zo = A3;
        for (int it = 0; it < NSI; it++) {
            launch_gemm(0, Z, Y, Tm, ND, ND, ND, sSq, sSq, sSq, ND, ND, ND, MODE_NST, nullptr, stream);
            launch_gemm(0, Y, Tm, Yo, ND, ND, ND, sSq, sSq, sSq, ND, ND, ND, MODE_PLAIN, nullptr, stream);
            launch_gemm(0, Tm, Z, Zo, ND, ND, ND, sSq, sSq, sSq, ND, ND, ND, MODE_PLAIN, nullptr, stream);
            float* tmp = Y; Y = Yo; Yo = tmp;
            tmp = Z; Z = Zo; Zo = tmp;
        }
        // Z_s ends in A3
    }
    // ---- phase T ----
    launch_gemm(1, tgt, tgt, A0, ND, ND, NR, sXin, sXin, sSq, ND, ND, ND, MODE_COV, nullptr, stream);
    frob_kernel<<<BATCH, 256, 0, stream>>>(A0, nrm_t);
    init_kernel<<<dim3(4096), 256, 0, stream>>>(A0, A2, nrm_t);
    {
        float* Y = A0; float* Yo = A1; float* Z = A2; float* Zo = A4;
        for (int it = 0; it < NSI; it++) {
            launch_gemm(0, Z, Y, Tm, ND, ND, ND, sSq, sSq, sSq, ND, ND, ND, MODE_NST, nullptr, stream);
            launch_gemm(0, Y, Tm, Yo, ND, ND, ND, sSq, sSq, sSq, ND, ND, ND, MODE_PLAIN, nullptr, stream);
            launch_gemm(0, Tm, Z, Zo, ND, ND, ND, sSq, sSq, sSq, ND, ND, ND, MODE_PLAIN, nullptr, stream);
            float* tmp = Y; Y = Yo; Yo = tmp;
            tmp = Z; Z = Zo; Zo = tmp;
        }
        // Z_t ends in A4
    }
    // ---- whiten: S_w = S Z_s / sqrt(nrm), T_w = T Z_t / sqrt(nrm) ----
    launch_gemm(0, src, A3, SW, NR, ND, ND, sXin, sSq, sXin, ND, ND, ND, MODE_SCALE, nrm_s, stream);
    launch_gemm(0, tgt, A4, TW, NR, ND, ND, sXin, sSq, sXin, ND, ND, ND, MODE_SCALE, nrm_t, stream);
    // ---- G = S_w^T S_w + T_w^T T_w ----
    launch_gemm(1, SW, SW, G, ND, ND, NR, sXin, sXin, sSq, ND, ND, ND, MODE_PLAIN, nullptr, stream);
    launch_gemm(1, TW, TW, G, ND, ND, NR, sXin, sXin, sSq, ND, ND, ND, MODE_ACC, nullptr, stream);
    // ---- eigensolver: tridiag + bisection + inverse iteration + back-transform ----
    tridiag_kernel<<<BATCH, 768, 0, stream>>>(G, dd, ee, tt);
    eigvals_kernel<<<BATCH, 64, 0, stream>>>(dd, ee, lam);
    invit_kernel<<<BATCH, 64, 0, stream>>>(dd, ee, lam, scr);
    orthbt_kernel<<<BATCH, 384, 0, stream>>>(yarr, G, tt, Qp);
    // ---- projections, Procrustes, output ----
    proj_kernel<<<dim3(2, BATCH), 256, 0, stream>>>(SW, Qp, Spp);
    proj_kernel<<<dim3(2, BATCH), 256, 0, stream>>>(TW, Qp, Tpp);
    polar_kernel<<<BATCH, 256, 0, stream>>>(Spp, Tpp, Rp);
    align_kernel<<<dim3(8, BATCH), 256, 0, stream>>>(SW, Spp, Rp, Qp, out);
    hipMemsetAsync((void*)accp, 0, 4, stream);
    cos_kernel<<<dim3(8192), 256, 0, stream>>>(out, tgt, accp);
    finalize_kernel<<<1, 1, 0, stream>>>(accp, out + (long)BATCH * NR * ND);
    (void)in_sizes; (void)n_in; (void)out_size; (void)ws_size;
}